// Round 5
// baseline (285.239 us; speedup 1.0000x reference)
//
#include <hip/hip_runtime.h>
#include <stdint.h>

// ---------- problem constants ----------
#define DIMC   512
#define NHEADS 16
#define HDIM   32
#define NWIN   64
#define NTOK   64
#define NBATCH 8
#define MROWS  (NBATCH * NWIN * NTOK)   // 32768

typedef unsigned short ushort_t;
typedef __attribute__((ext_vector_type(8))) short short8v;   // 8 bf16 = 4 VGPR
typedef __attribute__((ext_vector_type(4))) float f32x4;

__device__ inline ushort_t f2bf(float f) {           // round-to-nearest-even
    unsigned u = __float_as_uint(f);
    u += 0x7FFFu + ((u >> 16) & 1u);
    return (ushort_t)(u >> 16);
}
__device__ inline unsigned packbf2(float a, float b) {
    return ((unsigned)f2bf(a)) | (((unsigned)f2bf(b)) << 16);
}
__device__ inline void unpack8(uint4 u, float* f) {
    const unsigned a[4] = {u.x, u.y, u.z, u.w};
    #pragma unroll
    for (int j = 0; j < 4; ++j) {
        f[2*j+0] = __uint_as_float((a[j] & 0xFFFFu) << 16);
        f[2*j+1] = __uint_as_float(a[j] & 0xFFFF0000u);
    }
}

// async global->LDS, 16B per lane; LDS dest is wave-uniform base + lane*16
#define G2L16(gp, lp) __builtin_amdgcn_global_load_lds( \
    (const __attribute__((address_space(1))) unsigned int*)(gp), \
    (__attribute__((address_space(3))) unsigned int*)(lp), 16, 0, 0)

// ---------- fp32 -> bf16 bulk convert (vectorized) ----------
__global__ __launch_bounds__(256) void cvt_f32_bf16(
    const float* __restrict__ in, ushort_t* __restrict__ out, int n4)
{
    int i = blockIdx.x * 256 + threadIdx.x;
    if (i < n4) {
        float4 v = reinterpret_cast<const float4*>(in)[i];
        ushort4 o;
        o.x = f2bf(v.x); o.y = f2bf(v.y); o.z = f2bf(v.z); o.w = f2bf(v.w);
        reinterpret_cast<ushort4*>(out)[i] = o;
    }
}

// ---------- qkv bias = concat[q_bias, 0, v_bias] ----------
__global__ void build_qkv_bias(const float* __restrict__ qb,
                               const float* __restrict__ vb,
                               float* __restrict__ bias)
{
    int i = blockIdx.x * 256 + threadIdx.x;
    if (i < 3 * DIMC) {
        float v = 0.f;
        if (i < DIMC) v = qb[i];
        else if (i >= 2 * DIMC) v = vb[i - 2 * DIMC];
        bias[i] = v;
    }
}

// =====================================================================
// 8-phase 256x256 bf16 MFMA GEMM (T1+T2+T3+T4+T5), C = A·B^T + bias
// 512 threads = 8 waves (2M x 4N); per-wave output 128x64; BK=64.
// LDS 128 KiB: 2 dbuf x (256x64) x {A,B}. XOR-swizzle (16B slots):
// data (row, chunk) at slot chunk^(row&7); staging keeps LDS dest linear
// and pre-swizzles the per-lane GLOBAL source chunk.
// Per K-tile t, 4 phases: MFMA quadrants (m0-3,n0-1),(m0-3,n2-3),
// (m4-7,n0-1),(m4-7,n2-3); one half-tile staged per phase:
// ph0->A0(t+1), ph1->A1(t+1), ph2->B0(t+2), ph3->B1(t+2); counted
// vmcnt(4) once per tile (2 half-tiles in flight), never 0 mid-loop.
// =====================================================================
#define BARX() { asm volatile("" ::: "memory"); \
                 __builtin_amdgcn_s_barrier();  \
                 asm volatile("" ::: "memory"); }
#define LGKM0() asm volatile("s_waitcnt lgkmcnt(0)" ::: "memory")
#define VMW(n)  asm volatile("s_waitcnt vmcnt(" #n ")" ::: "memory")

#define STAGE(ls, g, bufi, t, h)                                             \
    {                                                                        \
        const int _k0 = (t) << 6;                                            \
        _Pragma("unroll")                                                    \
        for (int _r = 0; _r < 2; ++_r)                                       \
            G2L16(g + (size_t)((h) * 128 + _r * 64) * (size_t)K + _k0,       \
                  &ls[bufi][((h) * 128 + _r * 64 + wv * 8) * 64]);           \
    }

#define DSA(dst, bufi, mh)                                                   \
    _Pragma("unroll")                                                        \
    for (int _m = 0; _m < 4; ++_m) {                                         \
        _Pragma("unroll")                                                    \
        for (int _k = 0; _k < 2; ++_k) {                                     \
            const int _row = wr * 128 + ((mh) * 4 + _m) * 16 + (l & 15);     \
            const int _ps  = (_k * 4 + (l >> 4)) ^ (_row & 7);               \
            dst[_m * 2 + _k] = *reinterpret_cast<const short8v*>(            \
                reinterpret_cast<const char*>(lsA[bufi]) + _row * 128 + _ps * 16); \
        }                                                                    \
    }

#define DSB(dst, bufi, nh)                                                   \
    _Pragma("unroll")                                                        \
    for (int _n = 0; _n < 2; ++_n) {                                         \
        _Pragma("unroll")                                                    \
        for (int _k = 0; _k < 2; ++_k) {                                     \
            const int _row = wc * 64 + ((nh) * 2 + _n) * 16 + (l & 15);      \
            const int _ps  = (_k * 4 + (l >> 4)) ^ (_row & 7);               \
            dst[_n * 2 + _k] = *reinterpret_cast<const short8v*>(            \
                reinterpret_cast<const char*>(lsB[bufi]) + _row * 128 + _ps * 16); \
        }                                                                    \
    }

#define MMQ(af, bf, mo, no)                                                  \
    __builtin_amdgcn_s_setprio(1);                                           \
    _Pragma("unroll")                                                        \
    for (int _m = 0; _m < 4; ++_m) {                                         \
        _Pragma("unroll")                                                    \
        for (int _n = 0; _n < 2; ++_n) {                                     \
            _Pragma("unroll")                                                \
            for (int _k = 0; _k < 2; ++_k)                                   \
                acc[(mo) + _m][(no) + _n] =                                  \
                    __builtin_amdgcn_mfma_f32_16x16x32_bf16(                 \
                        af[_m * 2 + _k], bf[_n * 2 + _k],                    \
                        acc[(mo) + _m][(no) + _n], 0, 0, 0);                 \
        }                                                                    \
    }                                                                        \
    __builtin_amdgcn_s_setprio(0);

template<bool OUT_BF16>
__global__ __launch_bounds__(512, 2) void gemm_bt_8ph(
    const ushort_t* __restrict__ A, const ushort_t* __restrict__ B,
    const float* __restrict__ bias, void* __restrict__ C,
    int N, int K, int nx)
{
    __shared__ ushort_t lsA[2][256 * 64];   // 64 KB
    __shared__ ushort_t lsB[2][256 * 64];   // 64 KB

    const int tid = threadIdx.x;
    const int l   = tid & 63;
    const int wv  = tid >> 6;        // wave 0..7
    const int wr  = wv >> 2;         // M half   (0..1)
    const int wc  = wv & 3;          // N quarter (0..3)

    // bijective XCD swizzle (gridDim.x % 8 == 0)
    const int nwg = (int)gridDim.x;
    const int bid = (int)blockIdx.x;
    const int swz = (bid & 7) * (nwg >> 3) + (bid >> 3);
    const size_t mBase = (size_t)(swz / nx) * 256;
    const size_t nBase = (size_t)(swz % nx) * 256;

    f32x4 acc[8][4] = {};

    // staging lane geometry: lane covers row wv*8+(l>>3) of each 64-row round
    const int srow   = l >> 3;
    const int schunk = (l & 7) ^ srow;     // pre-swizzled global 16B chunk
    const ushort_t* gA = A + (mBase + (size_t)(wv * 8 + srow)) * (size_t)K + schunk * 8;
    const ushort_t* gB = B + (nBase + (size_t)(wv * 8 + srow)) * (size_t)K + schunk * 8;

    // ---- prologue: tile0 complete + B halves of tile1; vmcnt(4) keeps
    //      the last 2 half-tiles (4 loads) in flight ----
    STAGE(lsA, gA, 0, 0, 0); STAGE(lsA, gA, 0, 0, 1);
    STAGE(lsB, gB, 0, 0, 0); STAGE(lsB, gB, 0, 0, 1);
    STAGE(lsB, gB, 1, 1, 0); STAGE(lsB, gB, 1, 1, 1);
    VMW(4);
    BARX();

    short8v aF[8], bF[4], bF2[4];
    const int nt = K >> 6;
    for (int t = 0; t < nt; ++t) {
        const int buf = t & 1, nbuf = buf ^ 1;
        // ---- phase 0: quadrant (m0-3 x n0-1); stage A0(t+1) ----
        DSA(aF, buf, 0);
        DSB(bF, buf, 0);
        if (t + 1 < nt) STAGE(lsA, gA, nbuf, t + 1, 0);
        BARX(); LGKM0();
        MMQ(aF, bF, 0, 0);
        BARX();
        // ---- phase 1: (m0-3 x n2-3); stage A1(t+1) ----
        DSB(bF2, buf, 1);
        if (t + 1 < nt) STAGE(lsA, gA, nbuf, t + 1, 1);
        BARX(); LGKM0();
        MMQ(aF, bF2, 0, 2);
        BARX();
        // ---- phase 2: (m4-7 x n0-1); stage B0(t+2) (reuses aF regs) ----
        DSA(aF, buf, 1);
        if (t + 2 < nt) STAGE(lsB, gB, buf, t + 2, 0);
        BARX(); LGKM0();
        MMQ(aF, bF, 4, 0);
        BARX();
        // ---- phase 3: (m4-7 x n2-3); stage B1(t+2); per-tile counted wait ----
        if (t + 2 < nt) { STAGE(lsB, gB, buf, t + 2, 1); VMW(4); }
        else if (t + 1 < nt) { VMW(0); }
        BARX();
        MMQ(aF, bF2, 4, 2);
        BARX();
    }

    // ---- epilogue: C/D layout col = lane&15, row = (lane>>4)*4 + i ----
    const int c0 = l & 15;
    const int r0 = (l >> 4) * 4;
    #pragma unroll
    for (int n = 0; n < 4; ++n) {
        const size_t gn = nBase + (size_t)(wc * 64 + n * 16 + c0);
        const float bv = bias[gn];
        #pragma unroll
        for (int m = 0; m < 8; ++m) {
            #pragma unroll
            for (int i = 0; i < 4; ++i) {
                const size_t gm = mBase + (size_t)(wr * 128 + m * 16 + r0 + i);
                const float val = acc[m][n][i] + bv;
                if (OUT_BF16) ((ushort_t*)C)[gm * (size_t)N + gn] = f2bf(val);
                else          ((float*)C)  [gm * (size_t)N + gn] = val;
            }
        }
    }
}

// ---------- MFMA window attention: one wave per (b, h, w) ----------
// S^T = mfma(Kf, Qf) so P packs along k; out^T = mfma(Vf, Pf) so the
// epilogue packs along d and stores coalesced 64B rows.
__global__ __launch_bounds__(64, 3) void win_attn_mfma(
    const ushort_t* __restrict__ qkv,          // [32768][1536] bf16
    const float* __restrict__ logit_scale,     // [16]
    ushort_t* __restrict__ attn_out)           // [32768][512]  bf16
{
    __shared__ __align__(16) ushort_t lsP[64 * 64];   // P rows (swizzled); reused for out^T
    __shared__ __align__(16) ushort_t lsV[2 * 64 * 16]; // V halves [half][k][16]
    __shared__ float2 csT[8][8];                        // (pos, freqpair) -> (cos, sin)

    const int l = threadIdx.x;
    const int c = l & 15;          // frag row/col lane index
    const int g = l >> 4;          // k-chunk group 0..3
    const int blk = blockIdx.x;
    const int w = blk & 63;
    const int h = (blk >> 6) & 15;
    const int b = blk >> 10;
    const size_t R = ((size_t)(b * 64 + w)) * 64;      // first token row of window
    const ushort_t* qrow = qkv + R * 1536 + h * 32;

    // ---- issue V global->LDS early (linear LDS dest, strided global src) ----
    {
        const ushort_t* vbase = qrow + 1024;
        #pragma unroll
        for (int half = 0; half < 2; ++half)
            #pragma unroll
            for (int kg = 0; kg < 2; ++kg) {
                const ushort_t* gsrc = vbase + (size_t)(kg * 32 + (l >> 1)) * 1536
                                       + half * 16 + (l & 1) * 8;
                G2L16(gsrc, &lsV[half * 1024 + kg * 512]);
            }
    }

    // ---- cos/sin table: angle = pos * 10000^(-f/8) ----
    {
        const int pos = l >> 3, f = l & 7;
        const float inv = __expf(-(float)f * 1.1512925464970230f); // ln(10000)/8
        const float ang = (float)pos * inv;
        csT[pos][f] = make_float2(__cosf(ang), __sinf(ang));
    }

    const float sc = __expf(fmaxf(logit_scale[h], 4.6051701859880914f))
                     * 0.17677669529663687f;           // * 1/sqrt(32)

    // ---- load Q/K tiles, L2-norm (shfl), RoPE, pack bf16 frags ----
    short8v Qf[4], Kf[4];
    #pragma unroll
    for (int mi = 0; mi < 4; ++mi) {
        const int tok = mi * 16 + c;
        const ushort_t* qp = qrow + (size_t)tok * 1536 + g * 8;
        uint4 uq = *reinterpret_cast<const uint4*>(qp);
        uint4 uk = *reinterpret_cast<const uint4*>(qp + 512);
        float qv[8], kv[8];
        unpack8(uq, qv); unpack8(uk, kv);

        float sq = 0.f, sk = 0.f;
        #pragma unroll
        for (int d = 0; d < 8; ++d) { sq += qv[d] * qv[d]; sk += kv[d] * kv[d]; }
        sq += __shfl_xor(sq, 16); sq += __shfl_xor(sq, 32);   // full-row sumsq
        sk += __shfl_xor(sk, 16); sk += __shfl_xor(sk, 32);
        const float qs = sc * rsqrtf(fmaxf(sq, 1e-24f));
        const float ks =      rsqrtf(fmaxf(sk, 1e-24f));

        const int wh = tok >> 3, ww = tok & 7;
        const int axpos = (g >= 2) ? ww : wh;               // dims 16..31 use w-axis
        union { short8v v; unsigned u[4]; } pq, pk2;
        #pragma unroll
        for (int pp = 0; pp < 4; ++pp) {
            const float2 cs = csT[axpos][(g & 1) * 4 + pp];
            float a0 = qv[2*pp] * qs, a1 = qv[2*pp+1] * qs;
            const float q0 = a0 * cs.x - a1 * cs.y;
            const float q1 = a1 * cs.x + a0 * cs.y;
            a0 = kv[2*pp] * ks; a1 = kv[2*pp+1] * ks;
            const float k0 = a0 * cs.x - a1 * cs.y;
            const float k1 = a1 * cs.x + a0 * cs.y;
            pq.u[pp]  = packbf2(q0, q1);
            pk2.u[pp] = packbf2(k0, k1);
        }
        Qf[mi] = pq.v; Kf[mi] = pk2.v;
    }

    // ---- S^T = K · Q^T : tile (ki, qi); row=key, col=query ----
    f32x4 S[4][4];
    #pragma unroll
    for (int ki = 0; ki < 4; ++ki)
        #pragma unroll
        for (int qi = 0; qi < 4; ++qi)
            S[ki][qi] = __builtin_amdgcn_mfma_f32_16x16x32_bf16(
                Kf[ki], Qf[qi], (f32x4){0.f, 0.f, 0.f, 0.f}, 0, 0, 0);

    // ---- softmax per q-column (in-lane over ki,i + shfl over lane groups) ----
    float isum[4];
    #pragma unroll
    for (int qi = 0; qi < 4; ++qi) {
        float m = -1e30f;
        #pragma unroll
        for (int ki = 0; ki < 4; ++ki)
            #pragma unroll
            for (int i = 0; i < 4; ++i) m = fmaxf(m, S[ki][qi][i]);
        m = fmaxf(m, __shfl_xor(m, 16));
        m = fmaxf(m, __shfl_xor(m, 32));
        float sum = 0.f;
        #pragma unroll
        for (int ki = 0; ki < 4; ++ki)
            #pragma unroll
            for (int i = 0; i < 4; ++i) {
                const float p = __expf(S[ki][qi][i] - m);
                S[ki][qi][i] = p; sum += p;
            }
        sum += __shfl_xor(sum, 16); sum += __shfl_xor(sum, 32);
        isum[qi] = 1.0f / sum;
    }

    // ---- P -> LDS row-major [q][k] bf16, XOR-swizzled 16B slots ----
    #pragma unroll
    for (int qi = 0; qi < 4; ++qi) {
        const int q = qi * 16 + c;
        #pragma unroll
        for (int ki = 0; ki < 4; ++ki) {
            const int s2 = 2 * ki + (g >> 1);              // 16B slot of this b64
            const int byteoff = q * 128 + ((s2 ^ (q & 7)) * 16) + (g & 1) * 8;
            uint2 pk2;
            pk2.x = packbf2(S[ki][qi][0], S[ki][qi][1]);
            pk2.y = packbf2(S[ki][qi][2], S[ki][qi][3]);
            *reinterpret_cast<uint2*>(reinterpret_cast<char*>(lsP) + byteoff) = pk2;
        }
    }

    // ---- V frags (V^T rows): wait staging, scalar u16 gathers ----
    asm volatile("s_waitcnt vmcnt(0)" ::: "memory");
    short8v Vf[2][2];
    #pragma unroll
    for (int half = 0; half < 2; ++half)
        #pragma unroll
        for (int ki = 0; ki < 2; ++ki) {
            union { short8v v; ushort_t e[8]; } t;
            #pragma unroll
            for (int j = 0; j < 8; ++j)
                t.e[j] = lsV[half * 1024 + (ki * 32 + g * 8 + j) * 16 + c];
            Vf[half][ki] = t.v;
        }

    // ---- P frags (swizzled b128 reads) ----
    short8v Pf[4][2];
    #pragma unroll
    for (int ni = 0; ni < 4; ++ni) {
        const int q = ni * 16 + c;
        #pragma unroll
        for (int ki = 0; ki < 2; ++ki) {
            const int s2 = ki * 4 + g;
            Pf[ni][ki] = *reinterpret_cast<const short8v*>(
                reinterpret_cast<const char*>(lsP) + q * 128 + ((s2 ^ (q & 7)) * 16));
        }
    }

    // ---- out^T = V^T · P^T : tile (mi=d-half, ni=q-tile) ----
    f32x4 O[2][4];
    #pragma unroll
    for (int mi = 0; mi < 2; ++mi)
        #pragma unroll
        for (int ni = 0; ni < 4; ++ni) {
            f32x4 a = __builtin_amdgcn_mfma_f32_16x16x32_bf16(
                Vf[mi][0], Pf[ni][0], (f32x4){0.f, 0.f, 0.f, 0.f}, 0, 0, 0);
            O[mi][ni] = __builtin_amdgcn_mfma_f32_16x16x32_bf16(
                Vf[mi][1], Pf[ni][1], a, 0, 0, 0);
        }

    // ---- pack out rows (bf16, *isum) into reused lsP, swizzled ----
    __syncthreads();
    #pragma unroll
    for (int ni = 0; ni < 4; ++ni) {
        const int q = ni * 16 + c;
        const float is = isum[ni];
        #pragma unroll
        for (int mi = 0; mi < 2; ++mi) {
            const int s = 2 * mi + (g >> 1);               // 16B slot in 64B row
            const int byteoff = q * 64 + ((s ^ (q & 3)) * 16) + (g & 1) * 8;
            uint2 pk2;
            pk2.x = packbf2(O[mi][ni][0] * is, O[mi][ni][1] * is);
            pk2.y = packbf2(O[mi][ni][2] * is, O[mi][ni][3] * is);
            *reinterpret_cast<uint2*>(reinterpret_cast<char*>(lsP) + byteoff) = pk2;
        }
    }

    // ---- coalesced store: lane reads chunk (q, p), stores 16B ----
    const int qr0 = l >> 2, p = l & 3;
    ushort_t* obase = attn_out + R * 512 + h * 32;
    #pragma unroll
    for (int r = 0; r < 4; ++r) {
        const int q = qr0 + r * 16;
        uint4 row = *reinterpret_cast<const uint4*>(
            reinterpret_cast<const char*>(lsP) + q * 64 + ((p ^ (q & 3)) * 16));
        *reinterpret_cast<uint4*>(
            reinterpret_cast<char*>(obase + (size_t)q * 512) + p * 16) = row;
    }
}

// ---------- launch ----------
extern "C" void kernel_launch(void* const* d_in, const int* in_sizes, int n_in,
                              void* d_out, int out_size, void* d_ws, size_t ws_size,
                              hipStream_t stream)
{
    (void)in_sizes; (void)n_in; (void)out_size; (void)ws_size;
    const float* x     = (const float*)d_in[0];   // (8,64,64,512)
    const float* wqkv  = (const float*)d_in[1];   // (1536,512)
    const float* qb    = (const float*)d_in[2];   // (512)
    const float* vb    = (const float*)d_in[3];   // (512)
    const float* ls    = (const float*)d_in[4];   // (16,1,1,1)
    const float* wproj = (const float*)d_in[5];   // (512,512)
    const float* pb    = (const float*)d_in[6];   // (512)
    float* out = (float*)d_out;

    char* ws = (char*)d_ws;
    ushort_t* xb      = (ushort_t*)(ws);                    // 33,554,432 B
    ushort_t* wqkvb   = (ushort_t*)(ws + 33554432);         //  1,572,864 B
    ushort_t* wprojb  = (ushort_t*)(ws + 35127296);         //    524,288 B
    ushort_t* qkvb    = (ushort_t*)(ws + 35651584);         // 100,663,296 B
    ushort_t* attnb   = (ushort_t*)(ws + 136314880);        // 33,554,432 B
    float*    qkvbias = (float*)   (ws + 169869312);        //      6,144 B

    cvt_f32_bf16<<<16384, 256, 0, stream>>>(x,     xb,     16777216 / 4);
    cvt_f32_bf16<<<768,   256, 0, stream>>>(wqkv,  wqkvb,  786432   / 4);
    cvt_f32_bf16<<<256,   256, 0, stream>>>(wproj, wprojb, 262144   / 4);
    build_qkv_bias<<<6, 256, 0, stream>>>(qb, vb, qkvbias);

    // qkv = x @ Wqkv^T + bias   (M=32768, N=1536, K=512); 128x6 = 768 wg
    gemm_bt_8ph<true><<<768, 512, 0, stream>>>(
        xb, wqkvb, qkvbias, qkvb, 3 * DIMC, DIMC, 6);

    // per-window attention (MFMA)
    win_attn_mfma<<<NBATCH * NHEADS * NWIN, 64, 0, stream>>>(qkvb, ls, attnb);

    // out = attn @ Wproj^T + proj_bias  (M=32768, N=512, K=512); 128x2 = 256 wg
    gemm_bt_8ph<false><<<256, 512, 0, stream>>>(
        attnb, wprojb, pb, out, DIMC, DIMC, 2);
}

// Round 6
// 265.777 us; speedup vs baseline: 1.0732x; 1.0732x over previous
//
#include <hip/hip_runtime.h>
#include <stdint.h>

// ---------- problem constants ----------
#define DIMC   512
#define NHEADS 16
#define HDIM   32
#define NWIN   64
#define NTOK   64
#define NBATCH 8
#define MROWS  (NBATCH * NWIN * NTOK)   // 32768

typedef unsigned short ushort_t;
typedef __attribute__((ext_vector_type(8))) short short8v;   // 8 bf16 = 4 VGPR
typedef __attribute__((ext_vector_type(4))) float f32x4;

__device__ inline ushort_t f2bf(float f) {           // round-to-nearest-even
    unsigned u = __float_as_uint(f);
    u += 0x7FFFu + ((u >> 16) & 1u);
    return (ushort_t)(u >> 16);
}
__device__ inline unsigned packbf2(float a, float b) {
    return ((unsigned)f2bf(a)) | (((unsigned)f2bf(b)) << 16);
}
__device__ inline void unpack8(uint4 u, float* f) {
    const unsigned a[4] = {u.x, u.y, u.z, u.w};
    #pragma unroll
    for (int j = 0; j < 4; ++j) {
        f[2*j+0] = __uint_as_float((a[j] & 0xFFFFu) << 16);
        f[2*j+1] = __uint_as_float(a[j] & 0xFFFF0000u);
    }
}

// async global->LDS, 16B per lane; LDS dest is wave-uniform base + lane*16
#define G2L16(gp, lp) __builtin_amdgcn_global_load_lds( \
    (const __attribute__((address_space(1))) unsigned int*)(gp), \
    (__attribute__((address_space(3))) unsigned int*)(lp), 16, 0, 0)

// ---------- fused prep: all three fp32->bf16 converts in ONE launch ----------
// float4-unit ranges: x = 4,194,304 | wqkv = 196,608 | wproj = 65,536
#define XN4   4194304
#define WQN4  196608
#define WPN4  65536
__global__ __launch_bounds__(256) void prep_all(
    const float* __restrict__ x, const float* __restrict__ wqkv,
    const float* __restrict__ wproj,
    ushort_t* __restrict__ xb, ushort_t* __restrict__ wqkvb,
    ushort_t* __restrict__ wprojb)
{
    const int i = blockIdx.x * 256 + threadIdx.x;
    const float* src; ushort_t* dst; int idx;
    if (i < XN4)               { src = x;     dst = xb;     idx = i; }
    else if (i < XN4 + WQN4)   { src = wqkv;  dst = wqkvb;  idx = i - XN4; }
    else                       { src = wproj; dst = wprojb; idx = i - XN4 - WQN4; }
    float4 v = reinterpret_cast<const float4*>(src)[idx];
    ushort4 o;
    o.x = f2bf(v.x); o.y = f2bf(v.y); o.z = f2bf(v.z); o.w = f2bf(v.w);
    reinterpret_cast<ushort4*>(dst)[idx] = o;
}

// ---------- bf16 MFMA GEMM, C[m,n] = sum_k A[m,k]*B[n,k] + bias[n] ----------
// 128x128 tile, BK=64, 4 waves (2x2). 2-phase double-buffered LDS:
// STAGE(t+1) issued BEFORE compute(t), single barrier per K-step, so the
// global_load_lds latency hides under the 32 MFMAs. XOR-swizzled LDS
// (16B slots): data (row, chunk) at slot (chunk ^ (row&7)); staging keeps
// LDS dest linear and pre-swizzles the per-lane GLOBAL source.
// 1-D grid with bijective XCD swizzle (gridDim.x % 8 == 0).
// QKV_BIAS: bias = concat[b0(512), zeros(512), b1(512)] computed inline.
template<bool OUT_BF16, bool QKV_BIAS>
__global__ __launch_bounds__(256) void gemm_bt_2ph(
    const ushort_t* __restrict__ A, const ushort_t* __restrict__ B,
    const float* __restrict__ b0, const float* __restrict__ b1,
    void* __restrict__ C, int M, int N, int K, int nx)
{
    __shared__ ushort_t lsA[2][128 * 64];   // 32 KB
    __shared__ ushort_t lsB[2][128 * 64];   // 32 KB

    const int tid = threadIdx.x;
    const int l   = tid & 63;
    const int wv  = tid >> 6;        // wave id 0..3
    const int wr  = wv >> 1;         // wave row (2x2 wave grid)
    const int wc  = wv & 1;          // wave col

    // XCD-aware swizzle: orig%8 = XCD; give each XCD a contiguous tile chunk
    const int nwg = (int)gridDim.x;
    const int bid = (int)blockIdx.x;
    const int swz = (bid & 7) * (nwg >> 3) + (bid >> 3);
    const size_t mBase = (size_t)(swz / nx) * 128;
    const size_t nBase = (size_t)(swz % nx) * 128;

    f32x4 acc[4][4] = {};

    // staging geometry: wave wv covers rows wv*32 + j*8 .. +7, j=0..3
    const int rl    = l >> 3;             // row within 8-row group
    const int chunk = (l & 7) ^ rl;       // pre-swizzled col-chunk (16B units)
    const ushort_t* gA0 = A + (mBase + (size_t)(wv * 32 + rl)) * (size_t)K + chunk * 8;
    const ushort_t* gB0 = B + (nBase + (size_t)(wv * 32 + rl)) * (size_t)K + chunk * 8;

    auto STAGE = [&](int buf, int t) {
        const int k0 = t << 6;
        #pragma unroll
        for (int j = 0; j < 4; ++j) {
            G2L16(gA0 + (size_t)(j * 8) * (size_t)K + k0,
                  &lsA[buf][(wv * 32 + j * 8) * 64]);
            G2L16(gB0 + (size_t)(j * 8) * (size_t)K + k0,
                  &lsB[buf][(wv * 32 + j * 8) * 64]);
        }
    };

    auto COMPUTE = [&](int buf) {
        #pragma unroll
        for (int kk = 0; kk < 2; ++kk) {
            short8v aF[4], bF[4];
            #pragma unroll
            for (int m = 0; m < 4; ++m) {
                const int row = wr * 64 + m * 16 + (l & 15);
                const int ps  = (kk * 4 + (l >> 4)) ^ (row & 7);
                aF[m] = *reinterpret_cast<const short8v*>(
                    reinterpret_cast<const char*>(lsA[buf]) + row * 128 + ps * 16);
            }
            #pragma unroll
            for (int n = 0; n < 4; ++n) {
                const int row = wc * 64 + n * 16 + (l & 15);
                const int ps  = (kk * 4 + (l >> 4)) ^ (row & 7);
                bF[n] = *reinterpret_cast<const short8v*>(
                    reinterpret_cast<const char*>(lsB[buf]) + row * 128 + ps * 16);
            }
            #pragma unroll
            for (int m = 0; m < 4; ++m)
                #pragma unroll
                for (int n = 0; n < 4; ++n)
                    acc[m][n] = __builtin_amdgcn_mfma_f32_16x16x32_bf16(
                        aF[m], bF[n], acc[m][n], 0, 0, 0);
        }
    };

    const int nt = K >> 6;           // K-tiles
    STAGE(0, 0);
    __syncthreads();                 // drains vmcnt(0): tile 0 resident
    int cur = 0;
    for (int t = 0; t < nt - 1; ++t) {
        STAGE(cur ^ 1, t + 1);       // issue next tile early
        COMPUTE(cur);                // MFMA hides the staging latency
        __syncthreads();             // drains stage(t+1) + this tile's ds_reads
        cur ^= 1;
    }
    COMPUTE(cur);                    // last tile, no prefetch

    // epilogue: C/D layout col = lane&15, row = (lane>>4)*4 + i  [m89-verified]
    const int c0 = l & 15;
    const int r0 = (l >> 4) * 4;
    #pragma unroll
    for (int m = 0; m < 4; ++m) {
        #pragma unroll
        for (int n = 0; n < 4; ++n) {
            const size_t gn = nBase + (size_t)(wc * 64 + n * 16 + c0);
            float bv;
            if (QKV_BIAS) bv = (gn < 512) ? b0[gn]
                             : ((gn < 1024) ? 0.f : b1[gn - 1024]);
            else          bv = b0[gn];
            #pragma unroll
            for (int i = 0; i < 4; ++i) {
                const size_t gm = mBase + (size_t)(wr * 64 + m * 16 + r0 + i);
                const float val = acc[m][n][i] + bv;
                if (OUT_BF16) ((ushort_t*)C)[gm * (size_t)N + gn] = f2bf(val);
                else          ((float*)C)  [gm * (size_t)N + gn] = val;
            }
        }
    }
}

// ---------- MFMA window attention: one wave per (b, h, w) ----------
// S^T = mfma(Kf, Qf) so P packs along k; out^T = mfma(Vf, Pf) so the
// epilogue packs along d and stores coalesced 64B rows.
__global__ __launch_bounds__(64, 3) void win_attn_mfma(
    const ushort_t* __restrict__ qkv,          // [32768][1536] bf16
    const float* __restrict__ logit_scale,     // [16]
    ushort_t* __restrict__ attn_out)           // [32768][512]  bf16
{
    __shared__ __align__(16) ushort_t lsP[64 * 64];   // P rows (swizzled); reused for out^T
    __shared__ __align__(16) ushort_t lsV[2 * 64 * 16]; // V halves [half][k][16]
    __shared__ float2 csT[8][8];                        // (pos, freqpair) -> (cos, sin)

    const int l = threadIdx.x;
    const int c = l & 15;          // frag row/col lane index
    const int g = l >> 4;          // k-chunk group 0..3
    const int blk = blockIdx.x;
    const int w = blk & 63;
    const int h = (blk >> 6) & 15;
    const int b = blk >> 10;
    const size_t R = ((size_t)(b * 64 + w)) * 64;      // first token row of window
    const ushort_t* qrow = qkv + R * 1536 + h * 32;

    // ---- issue V global->LDS early (linear LDS dest, strided global src) ----
    {
        const ushort_t* vbase = qrow + 1024;
        #pragma unroll
        for (int half = 0; half < 2; ++half)
            #pragma unroll
            for (int kg = 0; kg < 2; ++kg) {
                const ushort_t* gsrc = vbase + (size_t)(kg * 32 + (l >> 1)) * 1536
                                       + half * 16 + (l & 1) * 8;
                G2L16(gsrc, &lsV[half * 1024 + kg * 512]);
            }
    }

    // ---- cos/sin table: angle = pos * 10000^(-f/8) ----
    {
        const int pos = l >> 3, f = l & 7;
        const float inv = __expf(-(float)f * 1.1512925464970230f); // ln(10000)/8
        const float ang = (float)pos * inv;
        csT[pos][f] = make_float2(__cosf(ang), __sinf(ang));
    }

    const float sc = __expf(fmaxf(logit_scale[h], 4.6051701859880914f))
                     * 0.17677669529663687f;           // * 1/sqrt(32)

    // ---- load Q/K tiles, L2-norm (shfl), RoPE, pack bf16 frags ----
    short8v Qf[4], Kf[4];
    #pragma unroll
    for (int mi = 0; mi < 4; ++mi) {
        const int tok = mi * 16 + c;
        const ushort_t* qp = qrow + (size_t)tok * 1536 + g * 8;
        uint4 uq = *reinterpret_cast<const uint4*>(qp);
        uint4 uk = *reinterpret_cast<const uint4*>(qp + 512);
        float qv[8], kv[8];
        unpack8(uq, qv); unpack8(uk, kv);

        float sq = 0.f, sk = 0.f;
        #pragma unroll
        for (int d = 0; d < 8; ++d) { sq += qv[d] * qv[d]; sk += kv[d] * kv[d]; }
        sq += __shfl_xor(sq, 16); sq += __shfl_xor(sq, 32);   // full-row sumsq
        sk += __shfl_xor(sk, 16); sk += __shfl_xor(sk, 32);
        const float qs = sc * rsqrtf(fmaxf(sq, 1e-24f));
        const float ks =      rsqrtf(fmaxf(sk, 1e-24f));

        const int wh = tok >> 3, ww = tok & 7;
        const int axpos = (g >= 2) ? ww : wh;               // dims 16..31 use w-axis
        union { short8v v; unsigned u[4]; } pq, pk2;
        #pragma unroll
        for (int pp = 0; pp < 4; ++pp) {
            const float2 cs = csT[axpos][(g & 1) * 4 + pp];
            float a0 = qv[2*pp] * qs, a1 = qv[2*pp+1] * qs;
            const float q0 = a0 * cs.x - a1 * cs.y;
            const float q1 = a1 * cs.x + a0 * cs.y;
            a0 = kv[2*pp] * ks; a1 = kv[2*pp+1] * ks;
            const float k0 = a0 * cs.x - a1 * cs.y;
            const float k1 = a1 * cs.x + a0 * cs.y;
            pq.u[pp]  = packbf2(q0, q1);
            pk2.u[pp] = packbf2(k0, k1);
        }
        Qf[mi] = pq.v; Kf[mi] = pk2.v;
    }

    // ---- S^T = K · Q^T : tile (ki, qi); row=key, col=query ----
    f32x4 S[4][4];
    #pragma unroll
    for (int ki = 0; ki < 4; ++ki)
        #pragma unroll
        for (int qi = 0; qi < 4; ++qi)
            S[ki][qi] = __builtin_amdgcn_mfma_f32_16x16x32_bf16(
                Kf[ki], Qf[qi], (f32x4){0.f, 0.f, 0.f, 0.f}, 0, 0, 0);

    // ---- softmax per q-column (in-lane over ki,i + shfl over lane groups) ----
    float isum[4];
    #pragma unroll
    for (int qi = 0; qi < 4; ++qi) {
        float m = -1e30f;
        #pragma unroll
        for (int ki = 0; ki < 4; ++ki)
            #pragma unroll
            for (int i = 0; i < 4; ++i) m = fmaxf(m, S[ki][qi][i]);
        m = fmaxf(m, __shfl_xor(m, 16));
        m = fmaxf(m, __shfl_xor(m, 32));
        float sum = 0.f;
        #pragma unroll
        for (int ki = 0; ki < 4; ++ki)
            #pragma unroll
            for (int i = 0; i < 4; ++i) {
                const float p = __expf(S[ki][qi][i] - m);
                S[ki][qi][i] = p; sum += p;
            }
        sum += __shfl_xor(sum, 16); sum += __shfl_xor(sum, 32);
        isum[qi] = 1.0f / sum;
    }

    // ---- P -> LDS row-major [q][k] bf16, XOR-swizzled 16B slots ----
    #pragma unroll
    for (int qi = 0; qi < 4; ++qi) {
        const int q = qi * 16 + c;
        #pragma unroll
        for (int ki = 0; ki < 4; ++ki) {
            const int s2 = 2 * ki + (g >> 1);              // 16B slot of this b64
            const int byteoff = q * 128 + ((s2 ^ (q & 7)) * 16) + (g & 1) * 8;
            uint2 pk2;
            pk2.x = packbf2(S[ki][qi][0], S[ki][qi][1]);
            pk2.y = packbf2(S[ki][qi][2], S[ki][qi][3]);
            *reinterpret_cast<uint2*>(reinterpret_cast<char*>(lsP) + byteoff) = pk2;
        }
    }

    // ---- V frags (V^T rows): wait staging, scalar u16 gathers ----
    asm volatile("s_waitcnt vmcnt(0)" ::: "memory");
    short8v Vf[2][2];
    #pragma unroll
    for (int half = 0; half < 2; ++half)
        #pragma unroll
        for (int ki = 0; ki < 2; ++ki) {
            union { short8v v; ushort_t e[8]; } t;
            #pragma unroll
            for (int j = 0; j < 8; ++j)
                t.e[j] = lsV[half * 1024 + (ki * 32 + g * 8 + j) * 16 + c];
            Vf[half][ki] = t.v;
        }

    // ---- P frags (swizzled b128 reads) ----
    short8v Pf[4][2];
    #pragma unroll
    for (int ni = 0; ni < 4; ++ni) {
        const int q = ni * 16 + c;
        #pragma unroll
        for (int ki = 0; ki < 2; ++ki) {
            const int s2 = ki * 4 + g;
            Pf[ni][ki] = *reinterpret_cast<const short8v*>(
                reinterpret_cast<const char*>(lsP) + q * 128 + ((s2 ^ (q & 7)) * 16));
        }
    }

    // ---- out^T = V^T · P^T : tile (mi=d-half, ni=q-tile) ----
    f32x4 O[2][4];
    #pragma unroll
    for (int mi = 0; mi < 2; ++mi)
        #pragma unroll
        for (int ni = 0; ni < 4; ++ni) {
            f32x4 a = __builtin_amdgcn_mfma_f32_16x16x32_bf16(
                Vf[mi][0], Pf[ni][0], (f32x4){0.f, 0.f, 0.f, 0.f}, 0, 0, 0);
            O[mi][ni] = __builtin_amdgcn_mfma_f32_16x16x32_bf16(
                Vf[mi][1], Pf[ni][1], a, 0, 0, 0);
        }

    // ---- pack out rows (bf16, *isum) into reused lsP, swizzled ----
    __syncthreads();
    #pragma unroll
    for (int ni = 0; ni < 4; ++ni) {
        const int q = ni * 16 + c;
        const float is = isum[ni];
        #pragma unroll
        for (int mi = 0; mi < 2; ++mi) {
            const int s = 2 * mi + (g >> 1);               // 16B slot in 64B row
            const int byteoff = q * 64 + ((s ^ (q & 3)) * 16) + (g & 1) * 8;
            uint2 pk2;
            pk2.x = packbf2(O[mi][ni][0] * is, O[mi][ni][1] * is);
            pk2.y = packbf2(O[mi][ni][2] * is, O[mi][ni][3] * is);
            *reinterpret_cast<uint2*>(reinterpret_cast<char*>(lsP) + byteoff) = pk2;
        }
    }

    // ---- coalesced store: lane reads chunk (q, p), stores 16B ----
    const int qr0 = l >> 2, p = l & 3;
    ushort_t* obase = attn_out + R * 512 + h * 32;
    #pragma unroll
    for (int r = 0; r < 4; ++r) {
        const int q = qr0 + r * 16;
        uint4 row = *reinterpret_cast<const uint4*>(
            reinterpret_cast<const char*>(lsP) + q * 64 + ((p ^ (q & 3)) * 16));
        *reinterpret_cast<uint4*>(
            reinterpret_cast<char*>(obase + (size_t)q * 512) + p * 16) = row;
    }
}

// ---------- launch ----------
extern "C" void kernel_launch(void* const* d_in, const int* in_sizes, int n_in,
                              void* d_out, int out_size, void* d_ws, size_t ws_size,
                              hipStream_t stream)
{
    (void)in_sizes; (void)n_in; (void)out_size; (void)ws_size;
    const float* x     = (const float*)d_in[0];   // (8,64,64,512)
    const float* wqkv  = (const float*)d_in[1];   // (1536,512)
    const float* qb    = (const float*)d_in[2];   // (512)
    const float* vb    = (const float*)d_in[3];   // (512)
    const float* ls    = (const float*)d_in[4];   // (16,1,1,1)
    const float* wproj = (const float*)d_in[5];   // (512,512)
    const float* pb    = (const float*)d_in[6];   // (512)
    float* out = (float*)d_out;

    char* ws = (char*)d_ws;
    ushort_t* xb      = (ushort_t*)(ws);                    // 33,554,432 B
    ushort_t* wqkvb   = (ushort_t*)(ws + 33554432);         //  1,572,864 B
    ushort_t* wprojb  = (ushort_t*)(ws + 35127296);         //    524,288 B
    ushort_t* qkvb    = (ushort_t*)(ws + 35651584);         // 100,663,296 B
    ushort_t* attnb   = (ushort_t*)(ws + 136314880);        // 33,554,432 B

    // fused prep: all three converts in one dispatch (17408 * 256 = 4,456,448)
    prep_all<<<17408, 256, 0, stream>>>(x, wqkv, wproj, xb, wqkvb, wprojb);

    // qkv = x @ Wqkv^T + concat[qb,0,vb]  (M=32768, N=1536, K=512); nwg=3072
    gemm_bt_2ph<true, true><<<3072, 256, 0, stream>>>(
        xb, wqkvb, qb, vb, qkvb, MROWS, 3 * DIMC, DIMC, 12);

    // per-window attention (MFMA)
    win_attn_mfma<<<NBATCH * NHEADS * NWIN, 64, 0, stream>>>(qkvb, ls, attnb);

    // out = attn @ Wproj^T + proj_bias  (M=32768, N=512, K=512); nwg=1024
    gemm_bt_2ph<false, false><<<1024, 256, 0, stream>>>(
        attnb, wprojb, pb, nullptr, out, MROWS, DIMC, DIMC, 4);
}